// Round 4
// baseline (336.901 us; speedup 1.0000x reference)
//
#include <hip/hip_runtime.h>
#include <stdint.h>

typedef __attribute__((ext_vector_type(8))) short short8;
typedef __attribute__((ext_vector_type(4))) float f32x4;

__device__ __forceinline__ unsigned short f2bf(float f) {
  unsigned u = __float_as_uint(f);
  u += 0x7FFF + ((u >> 16) & 1);
  return (unsigned short)(u >> 16);
}
__device__ __forceinline__ float bf2f(unsigned short h) {
  return __uint_as_float(((unsigned)h) << 16);
}

// ---------------- f32 -> bf16 convert (x4 vectorized) ----------------
__global__ __launch_bounds__(256) void k_cvt(const float* __restrict__ in,
                                             unsigned short* __restrict__ out, int n4) {
  int i = blockIdx.x * 256 + threadIdx.x;
  if (i >= n4) return;
  float4 v = ((const float4*)in)[i];
  ushort4 o;
  o.x = f2bf(v.x); o.y = f2bf(v.y); o.z = f2bf(v.z); o.w = f2bf(v.w);
  ((ushort4*)out)[i] = o;
}

// ---------------- zero the seq-pad columns of Vt ----------------
__global__ __launch_bounds__(256) void k_zpad(unsigned short* __restrict__ vt) {
  const int TOT = 768 * 64 * 27;
  int i = blockIdx.x * 256 + threadIdx.x;
  if (i >= TOT) return;
  int row = i / 27, c = i - row * 27;
  vt[row * 224 + 197 + c] = 0;
}

// ---------------- fused: x f32 -> bf16 + low = 2*X@A^T ----------------
__global__ __launch_bounds__(256) void k_lowcvt(const float* __restrict__ x,
                                                const float* __restrict__ lora_a,
                                                unsigned short* __restrict__ xbf,
                                                float* __restrict__ low, int M) {
  __shared__ float As[8 * 768];
  for (int i = threadIdx.x; i < 8 * 768; i += 256) As[i] = lora_a[i];
  __syncthreads();
  int w = threadIdx.x >> 6, l = threadIdx.x & 63;
  int m = blockIdx.x * 4 + w;
  if (m >= M) return;
  float acc[8] = {0, 0, 0, 0, 0, 0, 0, 0};
  for (int j = 0; j < 12; ++j) {
    int d = j * 64 + l;
    float xv = x[(size_t)m * 768 + d];
    xbf[(size_t)m * 768 + d] = f2bf(xv);
#pragma unroll
    for (int r = 0; r < 8; ++r) acc[r] += xv * As[r * 768 + d];
  }
#pragma unroll
  for (int r = 0; r < 8; ++r)
    for (int dd = 1; dd < 64; dd <<= 1) acc[r] += __shfl_xor(acc[r], dd);
  if (l == 0) {
#pragma unroll
    for (int r = 0; r < 8; ++r) low[m * 8 + r] = 2.0f * acc[r];
  }
}

// ---------------- rank-8 LoRA low = 2 * X @ A^T  (bf16 input) ----------------
__global__ __launch_bounds__(256) void k_low(const unsigned short* __restrict__ xin,
                                             const float* __restrict__ lora_a,
                                             float* __restrict__ low, int M) {
  __shared__ float As[8 * 768];
  for (int i = threadIdx.x; i < 8 * 768; i += 256) As[i] = lora_a[i];
  __syncthreads();
  int w = threadIdx.x >> 6, l = threadIdx.x & 63;
  int m = blockIdx.x * 4 + w;
  if (m >= M) return;
  float acc[8] = {0, 0, 0, 0, 0, 0, 0, 0};
  for (int j = 0; j < 12; ++j) {
    int d = j * 64 + l;
    float xv = bf2f(xin[(size_t)m * 768 + d]);
#pragma unroll
    for (int r = 0; r < 8; ++r) acc[r] += xv * As[r * 768 + d];
  }
#pragma unroll
  for (int r = 0; r < 8; ++r)
    for (int dd = 1; dd < 64; dd <<= 1) acc[r] += __shfl_xor(acc[r], dd);
  if (l == 0) {
#pragma unroll
    for (int r = 0; r < 8; ++r) low[m * 8 + r] = 2.0f * acc[r];
  }
}

// ---------------- 256x256 reg-staged double-buffered GEMM ----------------
// C[M,N] = A[M,768] x B[N,768]^T. 8 waves (2Mx4N), wave-tile 128x64, BK=64.
// Staging: global -> VGPR (plain dwordx4) -> ds_write_b128 into XOR-swizzled
// LDS ([row][chunk^(row&7)], 16B chunks). No global_load_lds, no inline asm;
// compiler-managed waitcnts; 2 __syncthreads per K-tile.
template <int MODE>
__global__ __launch_bounds__(512, 2) void k_gemmrs(
    const unsigned short* __restrict__ A, const unsigned short* __restrict__ Bw,
    const float* __restrict__ bias, const float* __restrict__ low,
    const float* __restrict__ lorab, unsigned short* __restrict__ Qg,
    unsigned short* __restrict__ Kg, unsigned short* __restrict__ Vtg,
    float* __restrict__ outp, int M, int nbx) {
  __shared__ __align__(16) char lds[131072];
  const int tid = threadIdx.x;
  const int w = tid >> 6, l = tid & 63;
  const int lr = l & 15, lg = l >> 4;
  const int wm = w >> 2, wn = w & 3;
  // bijective XCD swizzle (m204)
  const int nwg = gridDim.x;
  const int orig = blockIdx.x;
  const int qq = nwg >> 3, rr = nwg & 7, xcd = orig & 7;
  const int wgid = (xcd < rr ? xcd * (qq + 1) : rr * (qq + 1) + (xcd - rr) * qq) + (orig >> 3);
  const int bx = wgid % nbx, by = wgid / nbx;
  const int m0 = by * 256, n0 = bx * 256;

  f32x4 acc[8][4];
#pragma unroll
  for (int i = 0; i < 8; ++i)
#pragma unroll
    for (int j = 0; j < 4; ++j) acc[i][j] = (f32x4){0.f, 0.f, 0.f, 0.f};

  // staging map: thread -> 4 A-chunks + 4 B-chunks (row = tid>>3 + 64j, chunk = tid&7)
  const int srow = tid >> 3;
  const int sc = tid & 7;
  const int swzw = (sc ^ (srow & 7)) * 16;  // write byte offset of chunk within row
  const int Mc = M - 1;
  uint4 av[4], bv[4];

  auto LOADT = [&](int t) {
#pragma unroll
    for (int j = 0; j < 4; ++j) {
      int ra = m0 + srow + j * 64;
      if (ra > Mc) ra = Mc;
      av[j] = *(const uint4*)(A + (size_t)ra * 768 + t * 64 + sc * 8);
      int rb = n0 + srow + j * 64;
      bv[j] = *(const uint4*)(Bw + (size_t)rb * 768 + t * 64 + sc * 8);
    }
  };
  auto WRT = [&](int s) {
    char* pa = lds + s * 65536;
#pragma unroll
    for (int j = 0; j < 4; ++j) {
      int row = srow + j * 64;
      *(uint4*)(pa + row * 128 + swzw) = av[j];
      *(uint4*)(pa + 32768 + row * 128 + swzw) = bv[j];
    }
  };
  const int rsw = (lr & 7);  // read-side row-swizzle bits
  auto CMP = [&](int s) {
    const char* pa = lds + s * 65536;
#pragma unroll
    for (int ks = 0; ks < 2; ++ks) {
      short8 af[8], bfr[4];
      const int co = (((ks << 2) | lg) ^ rsw) * 16;
#pragma unroll
      for (int nf = 0; nf < 4; ++nf) {
        int row = wn * 64 + nf * 16 + lr;
        bfr[nf] = *(const short8*)(pa + 32768 + row * 128 + co);
      }
#pragma unroll
      for (int mf = 0; mf < 8; ++mf) {
        int row = wm * 128 + mf * 16 + lr;
        af[mf] = *(const short8*)(pa + row * 128 + co);
      }
#pragma unroll
      for (int mf = 0; mf < 8; ++mf)
#pragma unroll
        for (int nf = 0; nf < 4; ++nf)
          acc[mf][nf] = __builtin_amdgcn_mfma_f32_16x16x32_bf16(af[mf], bfr[nf], acc[mf][nf], 0, 0, 0);
    }
  };

  LOADT(0);
  WRT(0);
  __syncthreads();
  for (int t = 0; t < 12; ++t) {
    if (t + 1 < 12) LOADT(t + 1);
    CMP(t & 1);
    __syncthreads();
    if (t + 1 < 12) {
      WRT((t + 1) & 1);
      __syncthreads();
    }
  }

  // epilogue: bias + rank-8 LoRA; MODE 0 scatter to Q/K/Vt bf16, MODE 1 f32 out
  float bo[4];
  float4 lb0[4], lb1[4];
  int which[4], hh[4], hd[4], ocol[4];
#pragma unroll
  for (int nf = 0; nf < 4; ++nf) {
    int o = n0 + wn * 64 + nf * 16 + lr;
    ocol[nf] = o;
    bo[nf] = bias[o];
    const float4* lb4 = (const float4*)(lorab + (size_t)o * 8);
    lb0[nf] = lb4[0];
    lb1[nf] = lb4[1];
    if (MODE == 0) {
      which[nf] = o / 768;
      int within = o - which[nf] * 768;
      hh[nf] = within >> 6;
      hd[nf] = within & 63;
    }
  }
#pragma unroll
  for (int mf = 0; mf < 8; ++mf) {
#pragma unroll
    for (int v = 0; v < 4; ++v) {
      int m = m0 + wm * 128 + mf * 16 + lg * 4 + v;
      if (m < M) {
        const float4* lp4 = (const float4*)(low + (size_t)m * 8);
        float4 l0 = lp4[0], l1 = lp4[1];
        int b = m / 197;
        int n = m - b * 197;
#pragma unroll
        for (int nf = 0; nf < 4; ++nf) {
          float val = acc[mf][nf][v] + bo[nf];
          val += l0.x * lb0[nf].x + l0.y * lb0[nf].y + l0.z * lb0[nf].z + l0.w * lb0[nf].w;
          val += l1.x * lb1[nf].x + l1.y * lb1[nf].y + l1.z * lb1[nf].z + l1.w * lb1[nf].w;
          if (MODE == 0) {
            int bh = b * 12 + hh[nf];
            unsigned short hv = f2bf(val);
            if (which[nf] == 0)      Qg[(bh * 224 + n) * 64 + hd[nf]] = hv;
            else if (which[nf] == 1) Kg[(bh * 224 + n) * 64 + hd[nf]] = hv;
            else                     Vtg[(bh * 64 + hd[nf]) * 224 + n] = hv;
          } else {
            outp[(size_t)m * 768 + ocol[nf]] = val;
          }
        }
      }
    }
  }
}

// ---------------- attention: one block per (b,h), full-row softmax ----------------
__global__ __launch_bounds__(256) void k_attn(const unsigned short* __restrict__ Qg,
                                              const unsigned short* __restrict__ Kg,
                                              const unsigned short* __restrict__ Vtg,
                                              unsigned short* __restrict__ aout) {
  __shared__ __align__(16) unsigned short Ps[4][16 * 224];
  const int bh = blockIdx.x;
  const int b = bh / 12, h = bh - b * 12;
  const unsigned short* Qb = Qg + (size_t)bh * (224 * 64);
  const unsigned short* Kb = Kg + (size_t)bh * (224 * 64);
  const unsigned short* Vb = Vtg + (size_t)bh * (64 * 224);
  const int w = threadIdx.x >> 6, l = threadIdx.x & 63;
  const int lr = l & 15, lg = l >> 4;
  for (int t = w; t < 13; t += 4) {
    const int q0 = t * 16;
    short8 aq0 = *(const short8*)(Qb + (q0 + lr) * 64 + lg * 8);
    short8 aq1 = *(const short8*)(Qb + (q0 + lr) * 64 + 32 + lg * 8);
    f32x4 s[14];
#pragma unroll
    for (int jt = 0; jt < 14; ++jt) {
      f32x4 a = (f32x4){0.f, 0.f, 0.f, 0.f};
      short8 bk0 = *(const short8*)(Kb + (jt * 16 + lr) * 64 + lg * 8);
      short8 bk1 = *(const short8*)(Kb + (jt * 16 + lr) * 64 + 32 + lg * 8);
      a = __builtin_amdgcn_mfma_f32_16x16x32_bf16(aq0, bk0, a, 0, 0, 0);
      a = __builtin_amdgcn_mfma_f32_16x16x32_bf16(aq1, bk1, a, 0, 0, 0);
      s[jt] = a;
    }
    float mx[4] = {-3.0e38f, -3.0e38f, -3.0e38f, -3.0e38f};
#pragma unroll
    for (int jt = 0; jt < 14; ++jt) {
      bool valid = (jt * 16 + lr) < 197;
#pragma unroll
      for (int v = 0; v < 4; ++v) {
        float sv = valid ? s[jt][v] : -1.0e30f;
        s[jt][v] = sv;
        mx[v] = fmaxf(mx[v], sv);
      }
    }
#pragma unroll
    for (int v = 0; v < 4; ++v) {
      mx[v] = fmaxf(mx[v], __shfl_xor(mx[v], 1));
      mx[v] = fmaxf(mx[v], __shfl_xor(mx[v], 2));
      mx[v] = fmaxf(mx[v], __shfl_xor(mx[v], 4));
      mx[v] = fmaxf(mx[v], __shfl_xor(mx[v], 8));
    }
    float sum[4] = {0.f, 0.f, 0.f, 0.f};
    const float cc = 0.125f * 1.44269504088896341f;
#pragma unroll
    for (int jt = 0; jt < 14; ++jt)
#pragma unroll
      for (int v = 0; v < 4; ++v) {
        float pv = exp2f((s[jt][v] - mx[v]) * cc);
        s[jt][v] = pv;
        sum[v] += pv;
      }
#pragma unroll
    for (int v = 0; v < 4; ++v) {
      sum[v] += __shfl_xor(sum[v], 1);
      sum[v] += __shfl_xor(sum[v], 2);
      sum[v] += __shfl_xor(sum[v], 4);
      sum[v] += __shfl_xor(sum[v], 8);
    }
    float inv[4];
#pragma unroll
    for (int v = 0; v < 4; ++v) inv[v] = 1.0f / sum[v];
    unsigned short* pw = &Ps[w][0];
#pragma unroll
    for (int jt = 0; jt < 14; ++jt)
#pragma unroll
      for (int v = 0; v < 4; ++v)
        pw[(lg * 4 + v) * 224 + jt * 16 + lr] = f2bf(s[jt][v] * inv[v]);
    f32x4 oacc[4];
#pragma unroll
    for (int jo = 0; jo < 4; ++jo) oacc[jo] = (f32x4){0.f, 0.f, 0.f, 0.f};
#pragma unroll
    for (int kk = 0; kk < 7; ++kk) {
      short8 pa = *(const short8*)(pw + lr * 224 + kk * 32 + lg * 8);
#pragma unroll
      for (int jo = 0; jo < 4; ++jo) {
        short8 bv = *(const short8*)(Vb + (jo * 16 + lr) * 224 + kk * 32 + lg * 8);
        oacc[jo] = __builtin_amdgcn_mfma_f32_16x16x32_bf16(pa, bv, oacc[jo], 0, 0, 0);
      }
    }
#pragma unroll
    for (int jo = 0; jo < 4; ++jo)
#pragma unroll
      for (int v = 0; v < 4; ++v) {
        int n = q0 + lg * 4 + v;
        if (n < 197) aout[((size_t)(b * 197 + n)) * 768 + h * 64 + jo * 16 + lr] = f2bf(oacc[jo][v]);
      }
  }
}

extern "C" void kernel_launch(void* const* d_in, const int* in_sizes, int n_in,
                              void* d_out, int out_size, void* d_ws, size_t ws_size,
                              hipStream_t stream) {
  const float* x      = (const float*)d_in[0];
  const float* qkv_w  = (const float*)d_in[1];
  const float* qkv_b  = (const float*)d_in[2];
  const float* qkv_la = (const float*)d_in[3];
  const float* qkv_lb = (const float*)d_in[4];
  const float* out_w  = (const float*)d_in[5];
  const float* out_b  = (const float*)d_in[6];
  const float* out_la = (const float*)d_in[7];
  const float* out_lb = (const float*)d_in[8];
  float* out = (float*)d_out;

  const int M = 64 * 197;  // 12608
  char* p = (char*)d_ws;
  auto carve = [&](size_t bytes) {
    char* r = p;
    p += (bytes + 255) & ~(size_t)255;
    return r;
  };
  unsigned short* xbf  = (unsigned short*)carve((size_t)M * 768 * 2);
  unsigned short* qwbf = (unsigned short*)carve((size_t)2304 * 768 * 2);
  unsigned short* owbf = (unsigned short*)carve((size_t)768 * 768 * 2);
  float* lowq          = (float*)carve((size_t)M * 8 * 4);
  float* lowo          = (float*)carve((size_t)M * 8 * 4);
  unsigned short* Qg   = (unsigned short*)carve((size_t)768 * 224 * 64 * 2);
  unsigned short* Kg   = (unsigned short*)carve((size_t)768 * 224 * 64 * 2);
  unsigned short* Vtg  = (unsigned short*)carve((size_t)768 * 64 * 224 * 2);
  unsigned short* aout = xbf;  // reuse: x_bf16 dead after qkv GEMM

  int n4q = 2304 * 768 / 4, n4o = 768 * 768 / 4;
  k_cvt<<<(n4q + 255) / 256, 256, 0, stream>>>(qkv_w, qwbf, n4q);
  k_cvt<<<(n4o + 255) / 256, 256, 0, stream>>>(out_w, owbf, n4o);
  k_zpad<<<(768 * 64 * 27 + 255) / 256, 256, 0, stream>>>(Vtg);
  k_lowcvt<<<(M + 3) / 4, 256, 0, stream>>>(x, qkv_la, xbf, lowq, M);
  k_gemmrs<0><<<50 * 9, 512, 0, stream>>>(xbf, qwbf, qkv_b, lowq, qkv_lb, Qg, Kg, Vtg, nullptr, M, 9);
  k_attn<<<768, 256, 0, stream>>>(Qg, Kg, Vtg, aout);
  k_low<<<(M + 3) / 4, 256, 0, stream>>>(aout, out_la, lowo, M);
  k_gemmrs<1><<<50 * 3, 512, 0, stream>>>(aout, owbf, out_b, lowo, out_lb, nullptr, nullptr, nullptr, out, M, 3);
}